// Round 5
// baseline (1470.037 us; speedup 1.0000x reference)
//
#include <hip/hip_runtime.h>
#include <hip/hip_bf16.h>

// Problem constants (B,T,C,H,E = 8,2048,1024,16,64; TOP_K=38)
#define T_LEN 2048
#define B_DIM 8
#define C_DIM 1024
#define TOPK  38

typedef short  short8  __attribute__((ext_vector_type(8)));
typedef _Float16 half8 __attribute__((ext_vector_type(8)));
typedef float  floatx4 __attribute__((ext_vector_type(4)));

__device__ __forceinline__ float bf16_bits_to_f32(unsigned short u) {
  return __uint_as_float(((unsigned int)u) << 16);
}
__device__ __forceinline__ unsigned short f32_to_bf16_bits(float f) {
  unsigned int x = __float_as_uint(f);
  unsigned int r = x + 0x7fffu + ((x >> 16) & 1u);   // RNE
  return (unsigned short)(r >> 16);
}
__device__ __forceinline__ unsigned short f16b(_Float16 h) {
  return __builtin_bit_cast(unsigned short, h);
}

// ---------------------------------------------------------------- zero fill
__global__ __launch_bounds__(256) void zero_kernel(float* __restrict__ p, int n) {
  int i = blockIdx.x * 256 + threadIdx.x;
  if (i < n) p[i] = 0.0f;
}

// ---------------------------------------------------------------- unified GEMM
// Computes C[m,n] = sum_k A[m][k] * B[n][k] in MFMA, with staging variants.
// ASRC: 0 = f32 NT, split->fp16 pairs (K_logical = 2*KP)
//       1 = f32 NT, -> bf16            (K_logical = KP)
//       2 = bf16 NT                    (K_logical = KP)
// BSRC: 0 = W f32 [KP,N] row-major, on-the-fly transpose + scale + split->fp16
//       1 = W f32 [KP,N] row-major, on-the-fly transpose -> bf16
//       2 = f32 NT, split->fp16 (same as ASRC 0; for the Gram's K operand)
// EPI:  0 = f32 store: out = acc*scale + bias
//       1 = bf16 store: out = acc*scale + bias
//       2 = Gram diagonal reduce into meanv
#define BM 128
#define BN 128
#define LDP 72   // padded LDS row stride (elements); 72*2=144B, 16B-aligned rows

template <int ASRC, int BSRC, int EPI>
__global__ __launch_bounds__(256, 2) void gemm_kernel(
    const void* __restrict__ Av, const void* __restrict__ Bv,
    const float* __restrict__ bias, void* __restrict__ outv,
    float* __restrict__ meanv, int M, int N, int KP,
    long long aStride, long long bStride, float scale, float wscale) {
  constexpr bool SPLIT = (ASRC == 0);
  __shared__ __align__(16) unsigned short lA[BM * LDP];
  __shared__ __align__(16) unsigned short lB[BN * LDP];
  __shared__ float diag[256];

  const int tid = threadIdx.x;
  const int bm = blockIdx.x, bn = blockIdx.y, bz = blockIdx.z;

  const int lane = tid & 63;
  const int wid = tid >> 6;
  const int wm = wid >> 1, wn = wid & 1;   // 2x2 waves -> 64x64 tiles each
  const int lr = lane & 15, lg = lane >> 4;

  const int srow = tid >> 1;               // A staging: 2 threads per row
  const int shalf = tid & 1;

  floatx4 acc[4][4];
  #pragma unroll
  for (int i = 0; i < 4; ++i)
    #pragma unroll
    for (int j = 0; j < 4; ++j) { acc[i][j][0]=0.f; acc[i][j][1]=0.f; acc[i][j][2]=0.f; acc[i][j][3]=0.f; }

  const int nk = SPLIT ? (KP / 32) : (KP / 64);  // 64 logical k per tile
  for (int kt = 0; kt < nk; ++kt) {
    // ---- A staging into registers
    short8 va[4];
    if constexpr (ASRC == 0) {
      const float* A = (const float*)Av + (long long)bz * aStride;
      const float* pa = A + (long long)(bm * BM + srow) * KP + kt * 32 + shalf * 16;
      floatx4 f[4];
      #pragma unroll
      for (int j = 0; j < 4; ++j) f[j] = *(const floatx4*)(pa + j * 4);
      #pragma unroll
      for (int j4 = 0; j4 < 4; ++j4) {
        short8 v;
        #pragma unroll
        for (int pp = 0; pp < 4; ++pp) {
          int p = j4 * 4 + pp;
          float x = f[p >> 2][p & 3];
          _Float16 hi = (_Float16)x;
          _Float16 lo = (_Float16)(x - (float)hi);
          v[2 * pp]     = (short)f16b(hi);
          v[2 * pp + 1] = (short)f16b(lo);
        }
        va[j4] = v;
      }
    } else if constexpr (ASRC == 1) {
      const float* A = (const float*)Av;
      const float* pa = A + (long long)(bm * BM + srow) * KP + kt * 64 + shalf * 32;
      floatx4 f[8];
      #pragma unroll
      for (int j = 0; j < 8; ++j) f[j] = *(const floatx4*)(pa + j * 4);
      #pragma unroll
      for (int j4 = 0; j4 < 4; ++j4) {
        short8 v;
        #pragma unroll
        for (int i = 0; i < 8; ++i)
          v[i] = (short)f32_to_bf16_bits(f[j4 * 2 + (i >> 2)][i & 3]);
        va[j4] = v;
      }
    } else {
      const unsigned short* A = (const unsigned short*)Av;
      const unsigned short* pa = A + (long long)(bm * BM + srow) * KP + kt * 64 + shalf * 32;
      #pragma unroll
      for (int j = 0; j < 4; ++j) va[j] = *(const short8*)(pa + j * 8);
    }

    // ---- B staging into registers
    short8 vb[4];        // for BSRC==2 path
    floatx4 wf[8];       // for W paths
    if constexpr (BSRC == 2) {
      const float* B = (const float*)Bv + (long long)bz * bStride;
      const float* pb = B + (long long)(bn * BN + srow) * KP + kt * 32 + shalf * 16;
      floatx4 f[4];
      #pragma unroll
      for (int j = 0; j < 4; ++j) f[j] = *(const floatx4*)(pb + j * 4);
      #pragma unroll
      for (int j4 = 0; j4 < 4; ++j4) {
        short8 v;
        #pragma unroll
        for (int pp = 0; pp < 4; ++pp) {
          int p = j4 * 4 + pp;
          float x = f[p >> 2][p & 3];
          _Float16 hi = (_Float16)x;
          _Float16 lo = (_Float16)(x - (float)hi);
          v[2 * pp]     = (short)f16b(hi);
          v[2 * pp + 1] = (short)f16b(lo);
        }
        vb[j4] = v;
      }
    } else if constexpr (BSRC == 0) {
      // W [KP,N] f32; tile k-rows [kt*32, kt*32+32)
      const float* W = (const float*)Bv;
      int wr = tid >> 3, nc = (tid & 7) * 16;
      const float* pw = W + (long long)(kt * 32 + wr) * N + bn * BN + nc;
      #pragma unroll
      for (int j = 0; j < 4; ++j) wf[j] = *(const floatx4*)(pw + j * 4);
    } else if constexpr (BSRC == 1) {
      // W [KP,N] f32; tile k-rows [kt*64, kt*64+64)
      const float* W = (const float*)Bv;
      int wr = tid >> 2, nc = (tid & 3) * 32;
      const float* pw = W + (long long)(kt * 64 + wr) * N + bn * BN + nc;
      #pragma unroll
      for (int j = 0; j < 8; ++j) wf[j] = *(const floatx4*)(pw + j * 4);
    }

    __syncthreads();
    // ---- LDS writes
    #pragma unroll
    for (int j = 0; j < 4; ++j)
      *(short8*)&lA[srow * LDP + shalf * 32 + j * 8] = va[j];

    if constexpr (BSRC == 2) {
      #pragma unroll
      for (int j = 0; j < 4; ++j)
        *(short8*)&lB[srow * LDP + shalf * 32 + j * 8] = vb[j];
    } else if constexpr (BSRC == 0) {
      int wr = tid >> 3, nc = (tid & 7) * 16;
      #pragma unroll
      for (int s = 0; s < 16; ++s) {
        int j = (s + wr) & 15;                 // stagger to spread LDS banks
        float x = wf[j >> 2][j & 3] * wscale;
        _Float16 hi = (_Float16)x;
        _Float16 lo = (_Float16)(x - (float)hi);
        unsigned int pk = (unsigned int)f16b(hi) | ((unsigned int)f16b(lo) << 16);
        *(unsigned int*)&lB[(nc + j) * LDP + 2 * wr] = pk;
      }
    } else if constexpr (BSRC == 1) {
      int wr = tid >> 2, nc = (tid & 3) * 32;
      #pragma unroll
      for (int s = 0; s < 32; ++s) {
        int j = (s + wr) & 31;
        lB[(nc + j) * LDP + wr] = f32_to_bf16_bits(wf[j >> 2][j & 3]);
      }
    }
    __syncthreads();

    // ---- MFMA over the 64 logical k of this tile
    #pragma unroll
    for (int s = 0; s < 2; ++s) {
      short8 af[4], bf[4];
      #pragma unroll
      for (int mi = 0; mi < 4; ++mi)
        af[mi] = *(const short8*)&lA[(wm * 64 + mi * 16 + lr) * LDP + s * 32 + lg * 8];
      #pragma unroll
      for (int ni = 0; ni < 4; ++ni)
        bf[ni] = *(const short8*)&lB[(wn * 64 + ni * 16 + lr) * LDP + s * 32 + lg * 8];
      #pragma unroll
      for (int mi = 0; mi < 4; ++mi)
        #pragma unroll
        for (int ni = 0; ni < 4; ++ni) {
          if constexpr (SPLIT) {
            acc[mi][ni] = __builtin_amdgcn_mfma_f32_16x16x32_f16(
                __builtin_bit_cast(half8, af[mi]), __builtin_bit_cast(half8, bf[ni]),
                acc[mi][ni], 0, 0, 0);
          } else {
            acc[mi][ni] = __builtin_amdgcn_mfma_f32_16x16x32_bf16(
                af[mi], bf[ni], acc[mi][ni], 0, 0, 0);
          }
        }
    }
  }

  if constexpr (EPI == 2) {
    // Gram diagonal reduce: G[m][n] contributes to l = (m-n) mod T
    diag[tid] = 0.0f;
    __syncthreads();
    #pragma unroll
    for (int mi = 0; mi < 4; ++mi)
      #pragma unroll
      for (int ni = 0; ni < 4; ++ni)
        #pragma unroll
        for (int i = 0; i < 4; ++i) {
          int rloc = wm * 64 + mi * 16 + lg * 4 + i;
          int cloc = wn * 64 + ni * 16 + lr;
          atomicAdd(&diag[rloc - cloc + 127], acc[mi][ni][i]);
        }
    __syncthreads();
    if (tid < 255) {
      int l = (bm * BM - bn * BN - 127 + tid) & (T_LEN - 1);  // mod 2048
      atomicAdd(&meanv[bz * T_LEN + l], diag[tid]);
    }
  } else {
    float bvs[4];
    #pragma unroll
    for (int ni = 0; ni < 4; ++ni) {
      int gc = bn * BN + wn * 64 + ni * 16 + lr;
      bvs[ni] = bias ? bias[gc & (C_DIM - 1)] : 0.0f;
    }
    #pragma unroll
    for (int mi = 0; mi < 4; ++mi)
      #pragma unroll
      for (int ni = 0; ni < 4; ++ni) {
        int gc = bn * BN + wn * 64 + ni * 16 + lr;
        #pragma unroll
        for (int i = 0; i < 4; ++i) {
          int gr = bm * BM + wm * 64 + mi * 16 + lg * 4 + i;
          float v = acc[mi][ni][i] * scale + bvs[ni];
          long long idx = (long long)gr * N + gc;
          if constexpr (EPI == 0) ((float*)outv)[idx] = v;
          else                    ((unsigned short*)outv)[idx] = f32_to_bf16_bits(v);
        }
      }
  }
}

// ---------------------------------------------------------------- top-k + softmax
__global__ __launch_bounds__(256) void topk_softmax_kernel(
    const float* __restrict__ meanv, float* __restrict__ wgt, int* __restrict__ dly) {
  __shared__ float vals[T_LEN];
  __shared__ float swv[4];
  __shared__ int   swi[4];
  __shared__ float selw[TOPK];
  __shared__ int   seli[TOPK];
  int b = blockIdx.x, tid = threadIdx.x;
  for (int i = tid; i < T_LEN; i += 256) vals[i] = meanv[b * T_LEN + i] * (1.0f / 1024.0f);
  __syncthreads();
  for (int it = 0; it < TOPK; ++it) {
    float bv = -3.4e38f; int bi = T_LEN - 1;
    for (int i = tid; i < T_LEN; i += 256) {
      float v = vals[i];
      if (v > bv || (v == bv && i < bi)) { bv = v; bi = i; }
    }
    #pragma unroll
    for (int off = 32; off > 0; off >>= 1) {
      float ov = __shfl_down(bv, off);
      int   oi = __shfl_down(bi, off);
      if (ov > bv || (ov == bv && oi < bi)) { bv = ov; bi = oi; }
    }
    if ((tid & 63) == 0) { swv[tid >> 6] = bv; swi[tid >> 6] = bi; }
    __syncthreads();
    if (tid == 0) {
      #pragma unroll
      for (int w = 1; w < 4; ++w) {
        float ov = swv[w]; int oi = swi[w];
        if (ov > bv || (ov == bv && oi < bi)) { bv = ov; bi = oi; }
      }
      if (bi < 0) bi = 0; if (bi > T_LEN - 1) bi = T_LEN - 1;
      selw[it] = bv; seli[it] = bi;
      vals[bi] = -3.4e38f;
    }
    __syncthreads();
  }
  if (tid == 0) {
    float m = selw[0], s = 0.0f, e[TOPK];
    for (int i = 0; i < TOPK; ++i) { e[i] = expf(selw[i] - m); s += e[i]; }
    float inv = 1.0f / s;
    for (int i = 0; i < TOPK; ++i) { wgt[b * TOPK + i] = e[i] * inv; dly[b * TOPK + i] = seli[i]; }
  }
}

// ---------------------------------------------------------------- aggregation (+reference's reshape)
// V2[b, t'=h*128+l/16, c'=(l%16)*64+e] = sum_k w[b,k] * V[b, (l+d_k)%T, h*64+e]
__global__ __launch_bounds__(256) void aggregate_kernel(
    const unsigned short* __restrict__ V, const float* __restrict__ wgt,
    const int* __restrict__ dly, unsigned short* __restrict__ V2) {
  int b = blockIdx.y;
  int g = blockIdx.x * 256 + threadIdx.x;       // 0 .. T*C/8-1
  int c8 = g & 127;
  int tp = g >> 7;                              // output row t'
  int h = tp >> 7, lhi = tp & 127;
  int cp = c8 << 3;
  int e0 = cp & 63, lo = cp >> 6;
  int l = lhi * 16 + lo;
  int ch = h * 64 + e0;
  float acc[8];
  #pragma unroll
  for (int j = 0; j < 8; ++j) acc[j] = 0.0f;
  const long long vbase = (long long)b * T_LEN * C_DIM;
  for (int k = 0; k < TOPK; ++k) {
    float w = wgt[b * TOPK + k];
    int d = dly[b * TOPK + k];
    int ts = (l + d) & (T_LEN - 1);
    short8 vv = *(const short8*)(V + vbase + (long long)ts * C_DIM + ch);
    #pragma unroll
    for (int j = 0; j < 8; ++j) acc[j] += w * bf16_bits_to_f32((unsigned short)vv[j]);
  }
  short8 o;
  #pragma unroll
  for (int j = 0; j < 8; ++j) o[j] = (short)f32_to_bf16_bits(acc[j]);
  *(short8*)(V2 + vbase + (long long)tp * C_DIM + cp) = o;
}

// ---------------------------------------------------------------- launcher
extern "C" void kernel_launch(void* const* d_in, const int* in_sizes, int n_in,
                              void* d_out, int out_size, void* d_ws, size_t ws_size,
                              hipStream_t stream) {
  // Inputs/outputs are float32 (established rounds 3-4).
  const float* x  = (const float*)d_in[0];
  const float* Wq = (const float*)d_in[1];
  const float* bq = (const float*)d_in[2];
  const float* Wk = (const float*)d_in[3];
  const float* bk = (const float*)d_in[4];
  const float* Wv = (const float*)d_in[5];
  const float* bv = (const float*)d_in[6];
  const float* Wp = (const float*)d_in[7];
  const float* bp = (const float*)d_in[8];

  // Workspace (67.2 MB, within the proven >=69.2 MB budget):
  //   [0, 64MiB)  Qf (f32, 16384x1024)  -> after Gram: V bf16 [0,32MiB), V2 bf16 [32,64MiB)
  //   [64MiB, +64KiB) meanv ; then wgt, dly
  // Kf (f32, 16384x1024 = 64 MiB) lives in d_out until the final GEMM overwrites it.
  const size_t SZ_F32 = (size_t)B_DIM * T_LEN * C_DIM * 4;  // 64 MiB
  const size_t NEEDED = SZ_F32 + 65536 + 8192;
  if (ws_size < NEEDED) return;

  char* ws = (char*)d_ws;
  float* Qf = (float*)ws;
  float* meanv = (float*)(ws + SZ_F32);
  float* wgt   = (float*)(ws + SZ_F32 + 65536);
  int*   dly   = (int*)(ws + SZ_F32 + 65536 + 4096);
  float* Kf = (float*)d_out;
  unsigned short* V  = (unsigned short*)ws;                      // after Qf is dead
  unsigned short* V2 = (unsigned short*)(ws + SZ_F32 / 2);

  const int M = B_DIM * T_LEN;  // 16384

  zero_kernel<<<(B_DIM * T_LEN) / 256, 256, 0, stream>>>(meanv, B_DIM * T_LEN);

  dim3 pgrid(M / BM, C_DIM / BN, 1);           // (128, 8)
  dim3 ggrid(T_LEN / BM, T_LEN / BN, B_DIM);   // (16, 16, 8)
  dim3 agrid((T_LEN * C_DIM / 8) / 256, B_DIM);

  // Q = x*Wq + bq  (split-fp16, f32-accurate; W scaled x32 in staging, /32 in epilogue)
  gemm_kernel<0, 0, 0><<<pgrid, 256, 0, stream>>>(x, Wq, bq, Qf, nullptr,
      M, C_DIM, C_DIM, 0, 0, 1.0f / 32.0f, 32.0f);
  // K = x*Wk + bk -> d_out scratch
  gemm_kernel<0, 0, 0><<<pgrid, 256, 0, stream>>>(x, Wk, bk, Kf, nullptr,
      M, C_DIM, C_DIM, 0, 0, 1.0f / 32.0f, 32.0f);
  // Gram diag: meanv[b,l] += sum_t sum_c Q[t,c]*K[(t-l)%T,c]  (split-fp16 both sides)
  gemm_kernel<0, 2, 2><<<ggrid, 256, 0, stream>>>(Qf, Kf, nullptr, nullptr, meanv,
      T_LEN, T_LEN, C_DIM, (long long)T_LEN * C_DIM, (long long)T_LEN * C_DIM, 1.0f, 1.0f);

  topk_softmax_kernel<<<B_DIM, 256, 0, stream>>>(meanv, wgt, dly);

  // V = x*Wv + bv  (bf16 path; Qf region is dead now)
  gemm_kernel<1, 1, 1><<<pgrid, 256, 0, stream>>>(x, Wv, bv, V, nullptr,
      M, C_DIM, C_DIM, 0, 0, 1.0f, 1.0f);

  aggregate_kernel<<<agrid, 256, 0, stream>>>(V, wgt, dly, V2);

  // out = V2*Wp + bp -> d_out f32 (Kf dead)
  gemm_kernel<2, 1, 0><<<pgrid, 256, 0, stream>>>(V2, Wp, bp, d_out, nullptr,
      M, C_DIM, C_DIM, 0, 0, 1.0f, 1.0f);
}

// Round 6
// 766.258 us; speedup vs baseline: 1.9185x; 1.9185x over previous
//
#include <hip/hip_runtime.h>

// Problem constants (B,T,C,H,E = 8,2048,1024,16,64; TOP_K=38)
#define T_LEN 2048
#define B_DIM 8
#define C_DIM 1024
#define TOPK  38

typedef _Float16 half8 __attribute__((ext_vector_type(8)));
typedef float  floatx4 __attribute__((ext_vector_type(4)));
typedef unsigned int u32;

__device__ __forceinline__ void async16(const void* g, void* l) {
  __builtin_amdgcn_global_load_lds(
      (const __attribute__((address_space(1))) u32*)g,
      (__attribute__((address_space(3))) u32*)l, 16, 0, 0);
}

// ---------------------------------------------------------------- zero fill
__global__ __launch_bounds__(256) void zero_kernel(float* __restrict__ p, int n) {
  int i = blockIdx.x * 256 + threadIdx.x;
  if (i < n) p[i] = 0.0f;
}

// ---------------------------------------------------------------- x f32 -> fp16 (8/thread)
__global__ __launch_bounds__(256) void cvt_f16_kernel(
    const float* __restrict__ src, _Float16* __restrict__ dst, int n8) {
  int i = blockIdx.x * 256 + threadIdx.x;
  if (i >= n8) return;
  floatx4 a = ((const floatx4*)src)[i * 2];
  floatx4 b = ((const floatx4*)src)[i * 2 + 1];
  half8 o;
  #pragma unroll
  for (int j = 0; j < 4; ++j) { o[j] = (_Float16)a[j]; o[j + 4] = (_Float16)b[j]; }
  ((half8*)dst)[i] = o;
}

// ---------------------------------------------------------------- W [K,N] f32 -> Wt [N,K] fp16
__global__ __launch_bounds__(256) void wt_kernel(
    const float* __restrict__ src, _Float16* __restrict__ dst) {
  __shared__ _Float16 tile[64][65];
  int k0 = blockIdx.y * 64, n0 = blockIdx.x * 64;
  int tx = threadIdx.x & 63, ty = threadIdx.x >> 6;  // ty 0..3
  #pragma unroll
  for (int j = 0; j < 16; ++j) {
    int r = j * 4 + ty;
    tile[r][tx] = (_Float16)src[(size_t)(k0 + r) * C_DIM + n0 + tx];
  }
  __syncthreads();
  #pragma unroll
  for (int j = 0; j < 16; ++j) {
    int r = j * 4 + ty;
    dst[(size_t)(n0 + r) * C_DIM + k0 + tx] = tile[tx][r];
  }
}

// ---------------------------------------------------------------- fp16 NT GEMM (m97-style)
// C[m,n] = sum_k A[m*K+k]*B[n*K+k]; both operands fp16, K-contiguous.
// EPI: 0 = fp16 store + bias, 1 = f32 store + bias, 2 = Gram diagonal reduce
template <int EPI>
__global__ __launch_bounds__(256, 3) void gemm_f16_kernel(
    const _Float16* __restrict__ A, const _Float16* __restrict__ B,
    const float* __restrict__ bias, void* __restrict__ outv,
    float* __restrict__ meanv, int N, int K,
    long long aStride, long long bStride) {
  __shared__ __align__(16) _Float16 lA[128 * 64];
  __shared__ __align__(16) _Float16 lB[128 * 64];
  __shared__ float diag[256];

  const int tid = threadIdx.x;
  const int bm = blockIdx.x, bn = blockIdx.y, bz = blockIdx.z;
  const int lane = tid & 63, w = tid >> 6;
  const int wm = w >> 1, wn = w & 1;     // 2x2 waves -> 64x64 tiles
  const int lr = lane & 15, lg = lane >> 4;

  const _Float16* Ab = A + (long long)bz * aStride;
  const _Float16* Bb = B + (long long)bz * bStride;

  const int lrow = lane >> 3;            // 0..7
  const int lcol = (lane & 7) * 8;       // element col within 64

  const _Float16* pA[4];
  const _Float16* pB[4];
  _Float16* dA[4];
  _Float16* dB[4];
  #pragma unroll
  for (int j = 0; j < 4; ++j) {
    int r = w * 32 + j * 8;              // wave-uniform row base of this 8-row slab
    pA[j] = Ab + (long long)(bm * 128 + r + lrow) * K + lcol;
    pB[j] = Bb + (long long)(bn * 128 + r + lrow) * K + lcol;
    dA[j] = &lA[r * 64];                 // wave-uniform LDS dest (lane x 16B appended by HW)
    dB[j] = &lB[r * 64];
  }

  floatx4 acc[4][4];
  #pragma unroll
  for (int i = 0; i < 4; ++i)
    #pragma unroll
    for (int j = 0; j < 4; ++j) { acc[i][j][0]=0.f; acc[i][j][1]=0.f; acc[i][j][2]=0.f; acc[i][j][3]=0.f; }

  const int nk = K >> 6;
  for (int kt = 0; kt < nk; ++kt) {
    __syncthreads();                     // protect LDS vs previous iteration's reads
    #pragma unroll
    for (int j = 0; j < 4; ++j) {
      async16(pA[j], dA[j]);
      async16(pB[j], dB[j]);
      pA[j] += 64; pB[j] += 64;
    }
    __syncthreads();                     // compiler drains vmcnt before s_barrier
    #pragma unroll
    for (int s = 0; s < 2; ++s) {
      half8 af[4], bf[4];
      #pragma unroll
      for (int mi = 0; mi < 4; ++mi)
        af[mi] = *(const half8*)&lA[(wm * 64 + mi * 16 + lr) * 64 + s * 32 + lg * 8];
      #pragma unroll
      for (int ni = 0; ni < 4; ++ni)
        bf[ni] = *(const half8*)&lB[(wn * 64 + ni * 16 + lr) * 64 + s * 32 + lg * 8];
      #pragma unroll
      for (int mi = 0; mi < 4; ++mi)
        #pragma unroll
        for (int ni = 0; ni < 4; ++ni)
          acc[mi][ni] = __builtin_amdgcn_mfma_f32_16x16x32_f16(
              af[mi], bf[ni], acc[mi][ni], 0, 0, 0);
    }
  }

  if constexpr (EPI == 2) {
    // Gram diagonal reduce: G[m][n] contributes to l = (m-n) mod T
    diag[tid] = 0.0f;
    __syncthreads();
    #pragma unroll
    for (int mi = 0; mi < 4; ++mi)
      #pragma unroll
      for (int ni = 0; ni < 4; ++ni)
        #pragma unroll
        for (int i = 0; i < 4; ++i) {
          int rloc = wm * 64 + mi * 16 + lg * 4 + i;
          int cloc = wn * 64 + ni * 16 + lr;
          atomicAdd(&diag[rloc - cloc + 127], acc[mi][ni][i]);
        }
    __syncthreads();
    if (tid < 255) {
      int l = (bm * 128 - bn * 128 - 127 + tid) & (T_LEN - 1);  // mod 2048
      atomicAdd(&meanv[bz * T_LEN + l], diag[tid]);
    }
  } else {
    float bvs[4];
    #pragma unroll
    for (int ni = 0; ni < 4; ++ni) {
      int gc = bn * 128 + wn * 64 + ni * 16 + lr;
      bvs[ni] = bias ? bias[gc & (C_DIM - 1)] : 0.0f;
    }
    #pragma unroll
    for (int mi = 0; mi < 4; ++mi)
      #pragma unroll
      for (int ni = 0; ni < 4; ++ni) {
        int gc = bn * 128 + wn * 64 + ni * 16 + lr;
        #pragma unroll
        for (int i = 0; i < 4; ++i) {
          int gr = bm * 128 + wm * 64 + mi * 16 + lg * 4 + i;
          float v = acc[mi][ni][i] + bvs[ni];
          long long idx = (long long)gr * N + gc;
          if constexpr (EPI == 1) ((float*)outv)[idx] = v;
          else                    ((_Float16*)outv)[idx] = (_Float16)v;
        }
      }
  }
}

// ---------------------------------------------------------------- top-k + softmax
__global__ __launch_bounds__(256) void topk_softmax_kernel(
    const float* __restrict__ meanv, float* __restrict__ wgt, int* __restrict__ dly) {
  __shared__ float vals[T_LEN];
  __shared__ float swv[4];
  __shared__ int   swi[4];
  __shared__ float selw[TOPK];
  __shared__ int   seli[TOPK];
  int b = blockIdx.x, tid = threadIdx.x;
  for (int i = tid; i < T_LEN; i += 256) vals[i] = meanv[b * T_LEN + i] * (1.0f / 1024.0f);
  __syncthreads();
  for (int it = 0; it < TOPK; ++it) {
    float bv = -3.4e38f; int bi = T_LEN - 1;
    for (int i = tid; i < T_LEN; i += 256) {
      float v = vals[i];
      if (v > bv || (v == bv && i < bi)) { bv = v; bi = i; }
    }
    #pragma unroll
    for (int off = 32; off > 0; off >>= 1) {
      float ov = __shfl_down(bv, off);
      int   oi = __shfl_down(bi, off);
      if (ov > bv || (ov == bv && oi < bi)) { bv = ov; bi = oi; }
    }
    if ((tid & 63) == 0) { swv[tid >> 6] = bv; swi[tid >> 6] = bi; }
    __syncthreads();
    if (tid == 0) {
      #pragma unroll
      for (int ww = 1; ww < 4; ++ww) {
        float ov = swv[ww]; int oi = swi[ww];
        if (ov > bv || (ov == bv && oi < bi)) { bv = ov; bi = oi; }
      }
      if (bi < 0) bi = 0; if (bi > T_LEN - 1) bi = T_LEN - 1;
      selw[it] = bv; seli[it] = bi;
      vals[bi] = -3.4e38f;
    }
    __syncthreads();
  }
  if (tid == 0) {
    float m = selw[0], s = 0.0f, e[TOPK];
    for (int i = 0; i < TOPK; ++i) { e[i] = expf(selw[i] - m); s += e[i]; }
    float inv = 1.0f / s;
    for (int i = 0; i < TOPK; ++i) { wgt[b * TOPK + i] = e[i] * inv; dly[b * TOPK + i] = seli[i]; }
  }
}

// ---------------------------------------------------------------- aggregation (+reference's reshape)
// V2[b, t'=h*128+l/16, c'=(l%16)*64+e] = sum_k w[b,k] * V[b, (l+d_k)%T, h*64+e]
__global__ __launch_bounds__(256) void aggregate_kernel(
    const _Float16* __restrict__ V, const float* __restrict__ wgt,
    const int* __restrict__ dly, _Float16* __restrict__ V2) {
  int b = blockIdx.y;
  int g = blockIdx.x * 256 + threadIdx.x;       // 0 .. T*C/8-1
  int c8 = g & 127;
  int tp = g >> 7;                              // output row t'
  int h = tp >> 7, lhi = tp & 127;
  int cp = c8 << 3;
  int e0 = cp & 63, lo = cp >> 6;
  int l = lhi * 16 + lo;
  int ch = h * 64 + e0;
  float acc[8];
  #pragma unroll
  for (int j = 0; j < 8; ++j) acc[j] = 0.0f;
  const long long vbase = (long long)b * T_LEN * C_DIM;
  for (int k = 0; k < TOPK; ++k) {
    float w = wgt[b * TOPK + k];
    int d = dly[b * TOPK + k];
    int ts = (l + d) & (T_LEN - 1);
    half8 vv = *(const half8*)(V + vbase + (long long)ts * C_DIM + ch);
    #pragma unroll
    for (int j = 0; j < 8; ++j) acc[j] += w * (float)vv[j];
  }
  half8 o;
  #pragma unroll
  for (int j = 0; j < 8; ++j) o[j] = (_Float16)acc[j];
  *(half8*)(V2 + vbase + (long long)tp * C_DIM + cp) = o;
}

// ---------------------------------------------------------------- launcher
extern "C" void kernel_launch(void* const* d_in, const int* in_sizes, int n_in,
                              void* d_out, int out_size, void* d_ws, size_t ws_size,
                              hipStream_t stream) {
  const float* x  = (const float*)d_in[0];
  const float* Wq = (const float*)d_in[1];
  const float* bq = (const float*)d_in[2];
  const float* Wk = (const float*)d_in[3];
  const float* bk = (const float*)d_in[4];
  const float* Wv = (const float*)d_in[5];
  const float* bv = (const float*)d_in[6];
  const float* Wp = (const float*)d_in[7];
  const float* bp = (const float*)d_in[8];

  // d_out (64 MiB f32 out) doubles as scratch:
  //   [0, 32MiB)   xh fp16 (x converted)         -- dead after V-proj
  //   [32,34) Wqt  [34,36) Wkt  [36,38) Wvt  (fp16 [N,K])
  // ws (>= 64MiB + 72KiB, proven):
  //   [0, 32MiB)   Qh fp16 -> later V fp16
  //   [32, 64MiB)  Kh fp16 -> later V2 fp16
  //   Wpt fp16 goes to ws[0,2MiB) after V dies
  //   tail: meanv (64KiB), wgt, dly
  const size_t SZ_H = (size_t)B_DIM * T_LEN * C_DIM * 2;   // 32 MiB
  const size_t NEEDED = 2 * SZ_H + 65536 + 8192;
  if (ws_size < NEEDED) return;

  char* ws = (char*)d_ws;
  _Float16* Qh = (_Float16*)ws;
  _Float16* Kh = (_Float16*)(ws + SZ_H);
  float* meanv = (float*)(ws + 2 * SZ_H);
  float* wgt   = (float*)(ws + 2 * SZ_H + 65536);
  int*   dly   = (int*)(ws + 2 * SZ_H + 65536 + 4096);
  _Float16* V   = (_Float16*)ws;             // after Gram (Qh dead)
  _Float16* V2  = (_Float16*)(ws + SZ_H);    // after agg (Kh dead)
  _Float16* Wpt = (_Float16*)ws;             // after agg (V dead), 2 MiB

  char* dob = (char*)d_out;
  _Float16* xh  = (_Float16*)dob;
  _Float16* Wqt = (_Float16*)(dob + 32 * 1048576);
  _Float16* Wkt = (_Float16*)(dob + 34 * 1048576);
  _Float16* Wvt = (_Float16*)(dob + 36 * 1048576);

  const int M = B_DIM * T_LEN;  // 16384
  const long long TC = (long long)T_LEN * C_DIM;

  zero_kernel<<<(B_DIM * T_LEN) / 256, 256, 0, stream>>>(meanv, B_DIM * T_LEN);
  cvt_f16_kernel<<<(M * C_DIM / 8) / 256, 256, 0, stream>>>(x, xh, M * C_DIM / 8);

  dim3 tgrid(16, 16);
  wt_kernel<<<tgrid, 256, 0, stream>>>(Wq, Wqt);
  wt_kernel<<<tgrid, 256, 0, stream>>>(Wk, Wkt);
  wt_kernel<<<tgrid, 256, 0, stream>>>(Wv, Wvt);

  dim3 pgrid(M / 128, C_DIM / 128, 1);        // (128, 8)
  dim3 ggrid(T_LEN / 128, T_LEN / 128, B_DIM);// (16, 16, 8)
  dim3 agrid((T_LEN * C_DIM / 8) / 256, B_DIM);

  gemm_f16_kernel<0><<<pgrid, 256, 0, stream>>>(xh, Wqt, bq, Qh, nullptr, C_DIM, C_DIM, 0, 0);
  gemm_f16_kernel<0><<<pgrid, 256, 0, stream>>>(xh, Wkt, bk, Kh, nullptr, C_DIM, C_DIM, 0, 0);
  gemm_f16_kernel<2><<<ggrid, 256, 0, stream>>>(Qh, Kh, nullptr, nullptr, meanv, T_LEN, C_DIM, TC, TC);

  topk_softmax_kernel<<<B_DIM, 256, 0, stream>>>(meanv, wgt, dly);

  // V = xh @ Wvt + bv  (Qh dead after Gram; stream-ordered)
  gemm_f16_kernel<0><<<pgrid, 256, 0, stream>>>(xh, Wvt, bv, V, nullptr, C_DIM, C_DIM, 0, 0);

  aggregate_kernel<<<agrid, 256, 0, stream>>>(V, wgt, dly, V2);

  wt_kernel<<<tgrid, 256, 0, stream>>>(Wp, Wpt);  // V dead after agg

  // out = V2 @ Wpt + bp -> d_out f32 (xh + weight slots dead)
  gemm_f16_kernel<1><<<pgrid, 256, 0, stream>>>(V2, Wpt, bp, d_out, nullptr, C_DIM, C_DIM, 0, 0);
}

// Round 7
// 670.414 us; speedup vs baseline: 2.1927x; 1.1430x over previous
//
#include <hip/hip_runtime.h>

// Problem constants (B,T,C,H,E = 8,2048,1024,16,64; TOP_K=38)
#define T_LEN 2048
#define B_DIM 8
#define C_DIM 1024
#define TOPK  38

typedef _Float16 half8 __attribute__((ext_vector_type(8)));
typedef float  floatx4 __attribute__((ext_vector_type(4)));
typedef unsigned int u32;

__device__ __forceinline__ void async16(const void* g, void* l) {
  __builtin_amdgcn_global_load_lds(
      (const __attribute__((address_space(1))) u32*)g,
      (__attribute__((address_space(3))) u32*)l, 16, 0, 0);
}

// ---------------------------------------------------------------- zero fill
__global__ __launch_bounds__(256) void zero_kernel(float* __restrict__ p, int n) {
  int i = blockIdx.x * 256 + threadIdx.x;
  if (i < n) p[i] = 0.0f;
}

// ---------------------------------------------------------------- x f32 -> fp16 (8/thread)
__global__ __launch_bounds__(256) void cvt_f16_kernel(
    const float* __restrict__ src, _Float16* __restrict__ dst, int n8) {
  int i = blockIdx.x * 256 + threadIdx.x;
  if (i >= n8) return;
  floatx4 a = ((const floatx4*)src)[i * 2];
  floatx4 b = ((const floatx4*)src)[i * 2 + 1];
  half8 o;
  #pragma unroll
  for (int j = 0; j < 4; ++j) { o[j] = (_Float16)a[j]; o[j + 4] = (_Float16)b[j]; }
  ((half8*)dst)[i] = o;
}

// ---------------------------------------------------------------- W [K,N] f32 -> Wt [N,K] fp16 (batched x3)
__global__ __launch_bounds__(256) void wt3_kernel(
    const float* __restrict__ w0, const float* __restrict__ w1,
    const float* __restrict__ w2, _Float16* __restrict__ d0,
    _Float16* __restrict__ d1, _Float16* __restrict__ d2) {
  const float* src = blockIdx.z == 0 ? w0 : (blockIdx.z == 1 ? w1 : w2);
  _Float16*    dst = blockIdx.z == 0 ? d0 : (blockIdx.z == 1 ? d1 : d2);
  __shared__ _Float16 tile[64][65];
  int k0 = blockIdx.y * 64, n0 = blockIdx.x * 64;
  int tx = threadIdx.x & 63, ty = threadIdx.x >> 6;  // ty 0..3
  #pragma unroll
  for (int j = 0; j < 16; ++j) {
    int r = j * 4 + ty;
    tile[r][tx] = (_Float16)src[(size_t)(k0 + r) * C_DIM + n0 + tx];
  }
  __syncthreads();
  #pragma unroll
  for (int j = 0; j < 16; ++j) {
    int r = j * 4 + ty;
    dst[(size_t)(n0 + r) * C_DIM + k0 + tx] = tile[tx][r];
  }
}

// ---------------------------------------------------------------- fp16 NT GEMM (m97-style)
// C[m,n] = sum_k A[m*K+k]*B[n*K+k]; both operands fp16, K-contiguous.
// EPI: 0 = fp16 store + bias, 1 = f32 store + bias, 2 = Gram diagonal reduce
template <int EPI>
__global__ __launch_bounds__(256, 3) void gemm_f16_kernel(
    const _Float16* __restrict__ A, const _Float16* __restrict__ B,
    const float* __restrict__ bias, void* __restrict__ outv,
    float* __restrict__ meanv, int N, int K,
    long long aStride, long long bStride) {
  __shared__ __align__(16) _Float16 lA[128 * 64];
  __shared__ __align__(16) _Float16 lB[128 * 64];
  __shared__ float diag4[4][256];   // per-wave diagonal bins (EPI==2 only)

  const int tid = threadIdx.x;
  const int bm = blockIdx.x, bn = blockIdx.y, bz = blockIdx.z;
  const int lane = tid & 63, w = tid >> 6;
  const int wm = w >> 1, wn = w & 1;     // 2x2 waves -> 64x64 tiles
  const int lr = lane & 15, lg = lane >> 4;

  const _Float16* Ab = A + (long long)bz * aStride;
  const _Float16* Bb = B + (long long)bz * bStride;

  const int lrow = lane >> 3;            // 0..7
  const int lcol = (lane & 7) * 8;       // element col within 64

  const _Float16* pA[4];
  const _Float16* pB[4];
  _Float16* dA[4];
  _Float16* dB[4];
  #pragma unroll
  for (int j = 0; j < 4; ++j) {
    int r = w * 32 + j * 8;              // wave-uniform row base of this 8-row slab
    pA[j] = Ab + (long long)(bm * 128 + r + lrow) * K + lcol;
    pB[j] = Bb + (long long)(bn * 128 + r + lrow) * K + lcol;
    dA[j] = &lA[r * 64];                 // wave-uniform LDS dest (lane x 16B appended by HW)
    dB[j] = &lB[r * 64];
  }

  floatx4 acc[4][4];
  #pragma unroll
  for (int i = 0; i < 4; ++i)
    #pragma unroll
    for (int j = 0; j < 4; ++j) { acc[i][j][0]=0.f; acc[i][j][1]=0.f; acc[i][j][2]=0.f; acc[i][j][3]=0.f; }

  const int nk = K >> 6;
  for (int kt = 0; kt < nk; ++kt) {
    __syncthreads();                     // protect LDS vs previous iteration's reads
    #pragma unroll
    for (int j = 0; j < 4; ++j) {
      async16(pA[j], dA[j]);
      async16(pB[j], dB[j]);
      pA[j] += 64; pB[j] += 64;
    }
    __syncthreads();                     // compiler drains vmcnt before s_barrier
    #pragma unroll
    for (int s = 0; s < 2; ++s) {
      half8 af[4], bf[4];
      #pragma unroll
      for (int mi = 0; mi < 4; ++mi)
        af[mi] = *(const half8*)&lA[(wm * 64 + mi * 16 + lr) * 64 + s * 32 + lg * 8];
      #pragma unroll
      for (int ni = 0; ni < 4; ++ni)
        bf[ni] = *(const half8*)&lB[(wn * 64 + ni * 16 + lr) * 64 + s * 32 + lg * 8];
      #pragma unroll
      for (int mi = 0; mi < 4; ++mi)
        #pragma unroll
        for (int ni = 0; ni < 4; ++ni)
          acc[mi][ni] = __builtin_amdgcn_mfma_f32_16x16x32_f16(
              af[mi], bf[ni], acc[mi][ni], 0, 0, 0);
    }
  }

  if constexpr (EPI == 2) {
    // Diagonal reduce: G[m][n] contributes to l = (m-n) mod T.
    // d = rloc-cloc = (wm-wn)*64 + (mi-ni)*16 + (lg*4 + i) - lr  -- depends on (mi-ni, i) only.
    // Step 1: register pre-reduction 64 -> 28 values.
    float s[7][4];
    #pragma unroll
    for (int dd = 0; dd < 7; ++dd)
      #pragma unroll
      for (int i = 0; i < 4; ++i) s[dd][i] = 0.0f;
    #pragma unroll
    for (int mi = 0; mi < 4; ++mi)
      #pragma unroll
      for (int ni = 0; ni < 4; ++ni)
        #pragma unroll
        for (int i = 0; i < 4; ++i)
          s[mi - ni + 3][i] += acc[mi][ni][i];
    // Step 2: per-wave LDS bins (no cross-wave contention; <=4-way within wave).
    #pragma unroll
    for (int j = 0; j < 4; ++j) ((float*)diag4)[tid + j * 256] = 0.0f;
    __syncthreads();
    const int base = (wm - wn) * 64 + lg * 4 - lr + 127;
    #pragma unroll
    for (int dd = 0; dd < 7; ++dd)
      #pragma unroll
      for (int i = 0; i < 4; ++i)
        atomicAdd(&diag4[w][base + (dd - 3) * 16 + i], s[dd][i]);
    __syncthreads();
    // Step 3: merge waves + one global atomic per diagonal.
    if (tid < 255) {
      float tot = diag4[0][tid] + diag4[1][tid] + diag4[2][tid] + diag4[3][tid];
      int l = (bm * 128 - bn * 128 - 127 + tid) & (T_LEN - 1);  // mod 2048
      atomicAdd(&meanv[bz * T_LEN + l], tot);
    }
  } else {
    float bvs[4];
    #pragma unroll
    for (int ni = 0; ni < 4; ++ni) {
      int gc = bn * 128 + wn * 64 + ni * 16 + lr;
      bvs[ni] = bias ? bias[gc & (C_DIM - 1)] : 0.0f;
    }
    #pragma unroll
    for (int mi = 0; mi < 4; ++mi)
      #pragma unroll
      for (int ni = 0; ni < 4; ++ni) {
        int gc = bn * 128 + wn * 64 + ni * 16 + lr;
        #pragma unroll
        for (int i = 0; i < 4; ++i) {
          int gr = bm * 128 + wm * 64 + mi * 16 + lg * 4 + i;
          float v = acc[mi][ni][i] + bvs[ni];
          long long idx = (long long)gr * N + gc;
          if constexpr (EPI == 1) ((float*)outv)[idx] = v;
          else                    ((_Float16*)outv)[idx] = (_Float16)v;
        }
      }
  }
}

// ---------------------------------------------------------------- top-k + softmax
__global__ __launch_bounds__(256) void topk_softmax_kernel(
    const float* __restrict__ meanv, float* __restrict__ wgt, int* __restrict__ dly) {
  __shared__ float vals[T_LEN];
  __shared__ float swv[4];
  __shared__ int   swi[4];
  __shared__ float selw[TOPK];
  __shared__ int   seli[TOPK];
  int b = blockIdx.x, tid = threadIdx.x;
  for (int i = tid; i < T_LEN; i += 256) vals[i] = meanv[b * T_LEN + i] * (1.0f / 1024.0f);
  __syncthreads();
  for (int it = 0; it < TOPK; ++it) {
    float bv = -3.4e38f; int bi = T_LEN - 1;
    for (int i = tid; i < T_LEN; i += 256) {
      float v = vals[i];
      if (v > bv || (v == bv && i < bi)) { bv = v; bi = i; }
    }
    #pragma unroll
    for (int off = 32; off > 0; off >>= 1) {
      float ov = __shfl_down(bv, off);
      int   oi = __shfl_down(bi, off);
      if (ov > bv || (ov == bv && oi < bi)) { bv = ov; bi = oi; }
    }
    if ((tid & 63) == 0) { swv[tid >> 6] = bv; swi[tid >> 6] = bi; }
    __syncthreads();
    if (tid == 0) {
      #pragma unroll
      for (int ww = 1; ww < 4; ++ww) {
        float ov = swv[ww]; int oi = swi[ww];
        if (ov > bv || (ov == bv && oi < bi)) { bv = ov; bi = oi; }
      }
      if (bi < 0) bi = 0; if (bi > T_LEN - 1) bi = T_LEN - 1;
      selw[it] = bv; seli[it] = bi;
      vals[bi] = -3.4e38f;
    }
    __syncthreads();
  }
  if (tid == 0) {
    float m = selw[0], s = 0.0f, e[TOPK];
    for (int i = 0; i < TOPK; ++i) { e[i] = expf(selw[i] - m); s += e[i]; }
    float inv = 1.0f / s;
    for (int i = 0; i < TOPK; ++i) { wgt[b * TOPK + i] = e[i] * inv; dly[b * TOPK + i] = seli[i]; }
  }
}

// ---------------------------------------------------------------- aggregation (+reference's reshape)
// V2[b, t'=h*128+l/16, c'=(l%16)*64+e] = sum_k w[b,k] * V[b, (l+d_k)%T, h*64+e]
__global__ __launch_bounds__(256) void aggregate_kernel(
    const _Float16* __restrict__ V, const float* __restrict__ wgt,
    const int* __restrict__ dly, _Float16* __restrict__ V2) {
  int b = blockIdx.y;
  int g = blockIdx.x * 256 + threadIdx.x;       // 0 .. T*C/8-1
  int c8 = g & 127;
  int tp = g >> 7;                              // output row t'
  int h = tp >> 7, lhi = tp & 127;
  int cp = c8 << 3;
  int e0 = cp & 63, lo = cp >> 6;
  int l = lhi * 16 + lo;
  int ch = h * 64 + e0;
  float acc[8];
  #pragma unroll
  for (int j = 0; j < 8; ++j) acc[j] = 0.0f;
  const long long vbase = (long long)b * T_LEN * C_DIM;
  for (int k = 0; k < TOPK; ++k) {
    float w = wgt[b * TOPK + k];
    int d = dly[b * TOPK + k];
    int ts = (l + d) & (T_LEN - 1);
    half8 vv = *(const half8*)(V + vbase + (long long)ts * C_DIM + ch);
    #pragma unroll
    for (int j = 0; j < 8; ++j) acc[j] += w * (float)vv[j];
  }
  half8 o;
  #pragma unroll
  for (int j = 0; j < 8; ++j) o[j] = (_Float16)acc[j];
  *(half8*)(V2 + vbase + (long long)tp * C_DIM + cp) = o;
}

// ---------------------------------------------------------------- launcher
extern "C" void kernel_launch(void* const* d_in, const int* in_sizes, int n_in,
                              void* d_out, int out_size, void* d_ws, size_t ws_size,
                              hipStream_t stream) {
  const float* x  = (const float*)d_in[0];
  const float* Wq = (const float*)d_in[1];
  const float* bq = (const float*)d_in[2];
  const float* Wk = (const float*)d_in[3];
  const float* bk = (const float*)d_in[4];
  const float* Wv = (const float*)d_in[5];
  const float* bv = (const float*)d_in[6];
  const float* Wp = (const float*)d_in[7];
  const float* bp = (const float*)d_in[8];

  // d_out (64 MiB f32 out) doubles as scratch:
  //   [0, 32MiB)   xh fp16 (x converted)         -- dead after V-proj
  //   [32,34) Wqt  [34,36) Wkt  [36,38) Wvt  (fp16 [N,K])
  // ws (>= 64MiB + 72KiB, proven):
  //   [0, 32MiB)   Qh fp16 -> later V fp16, then Wpt
  //   [32, 64MiB)  Kh fp16 -> later V2 fp16
  //   tail: meanv (64KiB), wgt, dly
  const size_t SZ_H = (size_t)B_DIM * T_LEN * C_DIM * 2;   // 32 MiB
  const size_t NEEDED = 2 * SZ_H + 65536 + 8192;
  if (ws_size < NEEDED) return;

  char* ws = (char*)d_ws;
  _Float16* Qh = (_Float16*)ws;
  _Float16* Kh = (_Float16*)(ws + SZ_H);
  float* meanv = (float*)(ws + 2 * SZ_H);
  float* wgt   = (float*)(ws + 2 * SZ_H + 65536);
  int*   dly   = (int*)(ws + 2 * SZ_H + 65536 + 4096);
  _Float16* V   = (_Float16*)ws;             // after Gram (Qh dead)
  _Float16* V2  = (_Float16*)(ws + SZ_H);    // after agg (Kh dead)
  _Float16* Wpt = (_Float16*)ws;             // after agg (V dead), 2 MiB

  char* dob = (char*)d_out;
  _Float16* xh  = (_Float16*)dob;
  _Float16* Wqt = (_Float16*)(dob + 32 * 1048576);
  _Float16* Wkt = (_Float16*)(dob + 34 * 1048576);
  _Float16* Wvt = (_Float16*)(dob + 36 * 1048576);

  const int M = B_DIM * T_LEN;  // 16384
  const long long TC = (long long)T_LEN * C_DIM;

  zero_kernel<<<(B_DIM * T_LEN) / 256, 256, 0, stream>>>(meanv, B_DIM * T_LEN);
  cvt_f16_kernel<<<(M * C_DIM / 8) / 256, 256, 0, stream>>>(x, xh, M * C_DIM / 8);

  dim3 t3grid(16, 16, 3);
  wt3_kernel<<<t3grid, 256, 0, stream>>>(Wq, Wk, Wv, Wqt, Wkt, Wvt);

  dim3 pgrid(M / 128, C_DIM / 128, 1);        // (128, 8)
  dim3 ggrid(T_LEN / 128, T_LEN / 128, B_DIM);// (16, 16, 8)
  dim3 agrid((T_LEN * C_DIM / 8) / 256, B_DIM);
  dim3 tgrid(16, 16, 1);

  gemm_f16_kernel<0><<<pgrid, 256, 0, stream>>>(xh, Wqt, bq, Qh, nullptr, C_DIM, C_DIM, 0, 0);
  gemm_f16_kernel<0><<<pgrid, 256, 0, stream>>>(xh, Wkt, bk, Kh, nullptr, C_DIM, C_DIM, 0, 0);
  gemm_f16_kernel<2><<<ggrid, 256, 0, stream>>>(Qh, Kh, nullptr, nullptr, meanv, T_LEN, C_DIM, TC, TC);

  topk_softmax_kernel<<<B_DIM, 256, 0, stream>>>(meanv, wgt, dly);

  // V = xh @ Wvt + bv  (Qh dead after Gram; stream-ordered)
  gemm_f16_kernel<0><<<pgrid, 256, 0, stream>>>(xh, Wvt, bv, V, nullptr, C_DIM, C_DIM, 0, 0);

  aggregate_kernel<<<agrid, 256, 0, stream>>>(V, wgt, dly, V2);

  wt3_kernel<<<tgrid, 256, 0, stream>>>(Wp, Wp, Wp, Wpt, Wpt, Wpt);  // z=1 slice only

  // out = V2 @ Wpt + bp -> d_out f32 (xh + weight slots dead)
  gemm_f16_kernel<1><<<pgrid, 256, 0, stream>>>(V2, Wpt, bp, d_out, nullptr, C_DIM, C_DIM, 0, 0);
}